// Round 4
// baseline (143.484 us; speedup 1.0000x reference)
//
#include <hip/hip_runtime.h>
#include <hip/hip_cooperative_groups.h>
#include <math.h>

namespace cg = cooperative_groups;

#define NW 16
#define NEUR 32
#define TTAB 8192            // global F-table nodes over [0,1]
#define WSUB 0.0625f         // 1/16, exact in fp32
#define INV_SIGMA 200.0f     // 1/0.005
#define OMEGA 15.0f
#define WTHRESH 1e-5f
#define BLOCKS 512
#define THREADS 256
#define NODES_PER_BLOCK (TTAB / BLOCKS)   // 16

__device__ __forceinline__ float sigmoid_f(float z) {
    return 1.0f / (1.0f + __expf(-z));
}
__device__ __forceinline__ float tanh_fast(float z) {
    // z bounded here; tanh = 1 - 2/(e^{2z}+1)
    const float e = __expf(2.0f * z);
    return 1.0f - 2.0f / (e + 1.0f);
}

// win_c(x) * u_c(x) for window c (full MLP), 0 if masked/out-of-range.
__device__ float window_term(float x, int c,
                             const float* __restrict__ W1, const float* __restrict__ b1,
                             const float* __restrict__ W2, const float* __restrict__ b2,
                             const float* __restrict__ W3, const float* __restrict__ b3) {
    if (c < 0 || c >= NW) return 0.0f;
    const float s1 = sigmoid_f((x - (float)c * WSUB) * INV_SIGMA);
    const float s2 = sigmoid_f(-(x - (float)(c + 1) * WSUB) * INV_SIGMA);
    const float win = s1 * s2;
    if (win <= WTHRESH) return 0.0f;

    // subdomain normalization constants (exact dyadic, match reference fp64->fp32)
    float mean, sd;
    if (c == 0)            { mean = 0.03515625f; sd = 0.03515625f; }
    else if (c == NW - 1)  { mean = 0.96484375f; sd = 0.03515625f; }
    else                   { mean = ((float)c + 0.5f) * 0.0625f; sd = 0.0390625f; }
    const float xn = (x - mean) / sd;

    const float* __restrict__ W1c = W1 + c * NEUR;
    const float* __restrict__ b1c = b1 + c * NEUR;
    float h1[NEUR];
#pragma unroll
    for (int j = 0; j < NEUR; ++j)
        h1[j] = tanh_fast(fmaf(xn, W1c[j], b1c[j]));

    const float* __restrict__ W2c = W2 + c * NEUR * NEUR;  // [k][j]
    const float* __restrict__ b2c = b2 + c * NEUR;
    float h2[NEUR];
#pragma unroll
    for (int j = 0; j < NEUR; ++j) h2[j] = b2c[j];
#pragma unroll 4
    for (int k = 0; k < NEUR; ++k) {
        const float hk = h1[k];
        const float4* __restrict__ row = (const float4*)(W2c + k * NEUR);
#pragma unroll
        for (int q = 0; q < NEUR / 4; ++q) {
            const float4 wv = row[q];
            h2[q * 4 + 0] = fmaf(hk, wv.x, h2[q * 4 + 0]);
            h2[q * 4 + 1] = fmaf(hk, wv.y, h2[q * 4 + 1]);
            h2[q * 4 + 2] = fmaf(hk, wv.z, h2[q * 4 + 2]);
            h2[q * 4 + 3] = fmaf(hk, wv.w, h2[q * 4 + 3]);
        }
    }

    const float* __restrict__ W3c = W3 + c * NEUR;
    float acc = b3[c];
#pragma unroll
    for (int k = 0; k < NEUR; ++k)
        acc = fmaf(tanh_fast(h2[k]), W3c[k], acc);

    return win * acc;   // U_SD=1, U_MEAN=0
}

// Single cooperative kernel: phase 1 builds the pre-summed F table into ws,
// grid.sync, phase 2 stages F into LDS and evaluates all points.
__global__ __launch_bounds__(THREADS) void fbpinn_fused(
    const float* __restrict__ x,
    const float* __restrict__ W1, const float* __restrict__ b1,
    const float* __restrict__ W2, const float* __restrict__ b2,
    const float* __restrict__ W3, const float* __restrict__ b3,
    float* __restrict__ F_ws, float* __restrict__ out, int n) {
    __shared__ float F[TTAB];   // 32 KB; F[0..47] doubles as phase-1 scratch

    // ---- phase 1: 16 nodes/block x 3 window-offsets = 48 work items ----
    const int t = threadIdx.x;
    if (t < 3 * NODES_PER_BLOCK) {
        const int node_local = t / 3;
        const int d = t - 3 * node_local;
        const int g = blockIdx.x * NODES_PER_BLOCK + node_local;
        const float xg = (float)g * (1.0f / (float)(TTAB - 1));
        int i0 = (int)(xg * 16.0f);
        if (i0 > NW - 1) i0 = NW - 1;
        F[t] = window_term(xg, i0 - 1 + d, W1, b1, W2, b2, W3, b3);
    }
    __syncthreads();
    if (t < NODES_PER_BLOCK) {
        const float s = F[3 * t] + F[3 * t + 1] + F[3 * t + 2];
        F_ws[blockIdx.x * NODES_PER_BLOCK + t] = s;
    }

    cg::this_grid().sync();

    // ---- phase 2: stage full F table (32 KB) into LDS ----
    {
        const float4* __restrict__ src = (const float4*)F_ws;
        float4* dst = (float4*)F;
#pragma unroll
        for (int i = t; i < TTAB / 4; i += THREADS)
            dst[i] = src[i];
    }
    __syncthreads();

    // ---- eval: one lerp + tanh(15x) per point ----
    const int n4 = n >> 2;
    const int stride = gridDim.x * blockDim.x;
    for (int idx = blockIdx.x * blockDim.x + t; idx < n4; idx += stride) {
        const float4 xv = *(const float4*)(x + idx * 4);
        float4 r;
#pragma unroll
        for (int e = 0; e < 4; ++e) {
            const float xe = (&xv.x)[e];
            float tt = xe * (float)(TTAB - 1);
            tt = fminf(fmaxf(tt, 0.0f), (float)(TTAB - 1) - 0.5f);
            const int it = (int)tt;
            const float f = tt - (float)it;
            const float u0 = F[it];
            const float u1 = F[it + 1];
            const float u = fmaf(f, u1 - u0, u0);
            (&r.x)[e] = tanh_fast(OMEGA * xe) * u;
        }
        *(float4*)(out + idx * 4) = r;
    }
    if (blockIdx.x == 0) {
        const int tail = n & 3;
        if (t < tail) {
            const float xe = x[n4 * 4 + t];
            float tt = xe * (float)(TTAB - 1);
            tt = fminf(fmaxf(tt, 0.0f), (float)(TTAB - 1) - 0.5f);
            const int it = (int)tt;
            const float f = tt - (float)it;
            const float u = fmaf(f, F[it + 1] - F[it], F[it]);
            out[n4 * 4 + t] = tanh_fast(OMEGA * xe) * u;
        }
    }
}

extern "C" void kernel_launch(void* const* d_in, const int* in_sizes, int n_in,
                              void* d_out, int out_size, void* d_ws, size_t ws_size,
                              hipStream_t stream) {
    const float* x  = (const float*)d_in[0];
    const float* W1 = (const float*)d_in[1];
    const float* b1 = (const float*)d_in[2];
    const float* W2 = (const float*)d_in[3];
    const float* b2 = (const float*)d_in[4];
    const float* W3 = (const float*)d_in[5];
    const float* b3 = (const float*)d_in[6];
    float* out = (float*)d_out;
    float* F_ws = (float*)d_ws;   // TTAB floats = 32 KB
    int n = in_sizes[0];

    void* args[] = { (void*)&x, (void*)&W1, (void*)&b1, (void*)&W2, (void*)&b2,
                     (void*)&W3, (void*)&b3, (void*)&F_ws, (void*)&out, (void*)&n };
    hipLaunchCooperativeKernel((void*)fbpinn_fused, dim3(BLOCKS), dim3(THREADS),
                               args, 0, stream);
}

// Round 5
// 137.889 us; speedup vs baseline: 1.0406x; 1.0406x over previous
//
#include <hip/hip_runtime.h>
#include <hip/hip_cooperative_groups.h>
#include <math.h>

namespace cg = cooperative_groups;

#define NW 16
#define NEUR 32
#define TTAB 8192            // global F-table nodes over [0,1]
#define WSUB 0.0625f         // 1/16, exact in fp32
#define INV_SIGMA 200.0f     // 1/0.005
#define OMEGA 15.0f
#define WTHRESH 1e-5f
#define BLOCKS 512
#define THREADS 256
#define NODES_PER_BLOCK (TTAB / BLOCKS)   // 16

__device__ __forceinline__ float sigmoid_f(float z) {
    return 1.0f / (1.0f + __expf(-z));
}
__device__ __forceinline__ float tanh_fast(float z) {
    // z bounded here; tanh = 1 - 2/(e^{2z}+1)
    const float e = __expf(2.0f * z);
    return 1.0f - 2.0f / (e + 1.0f);
}

// win_c(x) * u_c(x) for window c (full MLP), 0 if masked/out-of-range.
// Register-lean: layer-2 computed 4 outputs at a time and consumed
// immediately into the W3 dot product -> ~45 live floats, no spill.
__device__ __forceinline__ float window_term(
    float x, int c,
    const float* __restrict__ W1, const float* __restrict__ b1,
    const float* __restrict__ W2, const float* __restrict__ b2,
    const float* __restrict__ W3, const float* __restrict__ b3) {
    if (c < 0 || c >= NW) return 0.0f;
    const float s1 = sigmoid_f((x - (float)c * WSUB) * INV_SIGMA);
    const float s2 = sigmoid_f(-(x - (float)(c + 1) * WSUB) * INV_SIGMA);
    const float win = s1 * s2;
    if (win <= WTHRESH) return 0.0f;

    // subdomain normalization constants (exact dyadic, match reference fp64->fp32)
    float mean, sd;
    if (c == 0)            { mean = 0.03515625f; sd = 0.03515625f; }
    else if (c == NW - 1)  { mean = 0.96484375f; sd = 0.03515625f; }
    else                   { mean = ((float)c + 0.5f) * 0.0625f; sd = 0.0390625f; }
    const float xn = (x - mean) / sd;

    const float* __restrict__ W1c = W1 + c * NEUR;
    const float* __restrict__ b1c = b1 + c * NEUR;
    float h1[NEUR];
#pragma unroll
    for (int j = 0; j < NEUR; ++j)
        h1[j] = tanh_fast(fmaf(xn, W1c[j], b1c[j]));

    const float* __restrict__ W2c = W2 + c * NEUR * NEUR;  // [k][j]
    const float* __restrict__ b2c = b2 + c * NEUR;
    const float* __restrict__ W3c = W3 + c * NEUR;
    float acc = b3[c];
#pragma unroll
    for (int j = 0; j < NEUR; j += 4) {
        float a0 = b2c[j], a1 = b2c[j + 1], a2 = b2c[j + 2], a3 = b2c[j + 3];
#pragma unroll
        for (int k = 0; k < NEUR; ++k) {
            const float hk = h1[k];
            const float4 wv = *(const float4*)(W2c + k * NEUR + j);
            a0 = fmaf(hk, wv.x, a0);
            a1 = fmaf(hk, wv.y, a1);
            a2 = fmaf(hk, wv.z, a2);
            a3 = fmaf(hk, wv.w, a3);
        }
        acc = fmaf(tanh_fast(a0), W3c[j],     acc);
        acc = fmaf(tanh_fast(a1), W3c[j + 1], acc);
        acc = fmaf(tanh_fast(a2), W3c[j + 2], acc);
        acc = fmaf(tanh_fast(a3), W3c[j + 3], acc);
    }

    return win * acc;   // U_SD=1, U_MEAN=0
}

// Single cooperative kernel: phase 1 builds the pre-summed F table into ws,
// grid.sync, phase 2 stages F into LDS and evaluates all points.
__global__ __launch_bounds__(THREADS, 2) void fbpinn_fused(
    const float* __restrict__ x,
    const float* __restrict__ W1, const float* __restrict__ b1,
    const float* __restrict__ W2, const float* __restrict__ b2,
    const float* __restrict__ W3, const float* __restrict__ b3,
    float* __restrict__ F_ws, float* __restrict__ out, int n) {
    __shared__ float F[TTAB];   // 32 KB; F[0..47] doubles as phase-1 scratch

    // ---- phase 1: 16 nodes/block x 3 window-offsets = 48 work items ----
    const int t = threadIdx.x;
    if (t < 3 * NODES_PER_BLOCK) {
        const int node_local = t / 3;
        const int d = t - 3 * node_local;
        const int g = blockIdx.x * NODES_PER_BLOCK + node_local;
        const float xg = (float)g * (1.0f / (float)(TTAB - 1));
        int i0 = (int)(xg * 16.0f);
        if (i0 > NW - 1) i0 = NW - 1;
        F[t] = window_term(xg, i0 - 1 + d, W1, b1, W2, b2, W3, b3);
    }
    __syncthreads();
    if (t < NODES_PER_BLOCK) {
        const float s = F[3 * t] + F[3 * t + 1] + F[3 * t + 2];
        F_ws[blockIdx.x * NODES_PER_BLOCK + t] = s;
    }

    cg::this_grid().sync();

    // ---- phase 2: stage full F table (32 KB) into LDS ----
    {
        const float4* __restrict__ src = (const float4*)F_ws;
        float4* dst = (float4*)F;
#pragma unroll
        for (int i = t; i < TTAB / 4; i += THREADS)
            dst[i] = src[i];
    }
    __syncthreads();

    // ---- eval: one lerp + tanh(15x) per point ----
    const int n4 = n >> 2;
    const int stride = gridDim.x * blockDim.x;
    for (int idx = blockIdx.x * blockDim.x + t; idx < n4; idx += stride) {
        const float4 xv = *(const float4*)(x + idx * 4);
        float4 r;
#pragma unroll
        for (int e = 0; e < 4; ++e) {
            const float xe = (&xv.x)[e];
            float tt = xe * (float)(TTAB - 1);
            tt = fminf(fmaxf(tt, 0.0f), (float)(TTAB - 1) - 0.5f);
            const int it = (int)tt;
            const float f = tt - (float)it;
            const float u0 = F[it];
            const float u1 = F[it + 1];
            const float u = fmaf(f, u1 - u0, u0);
            (&r.x)[e] = tanh_fast(OMEGA * xe) * u;
        }
        *(float4*)(out + idx * 4) = r;
    }
    if (blockIdx.x == 0) {
        const int tail = n & 3;
        if (t < tail) {
            const float xe = x[n4 * 4 + t];
            float tt = xe * (float)(TTAB - 1);
            tt = fminf(fmaxf(tt, 0.0f), (float)(TTAB - 1) - 0.5f);
            const int it = (int)tt;
            const float f = tt - (float)it;
            const float u = fmaf(f, F[it + 1] - F[it], F[it]);
            out[n4 * 4 + t] = tanh_fast(OMEGA * xe) * u;
        }
    }
}

extern "C" void kernel_launch(void* const* d_in, const int* in_sizes, int n_in,
                              void* d_out, int out_size, void* d_ws, size_t ws_size,
                              hipStream_t stream) {
    const float* x  = (const float*)d_in[0];
    const float* W1 = (const float*)d_in[1];
    const float* b1 = (const float*)d_in[2];
    const float* W2 = (const float*)d_in[3];
    const float* b2 = (const float*)d_in[4];
    const float* W3 = (const float*)d_in[5];
    const float* b3 = (const float*)d_in[6];
    float* out = (float*)d_out;
    float* F_ws = (float*)d_ws;   // TTAB floats = 32 KB
    int n = in_sizes[0];

    void* args[] = { (void*)&x, (void*)&W1, (void*)&b1, (void*)&W2, (void*)&b2,
                     (void*)&W3, (void*)&b3, (void*)&F_ws, (void*)&out, (void*)&n };
    hipLaunchCooperativeKernel((void*)fbpinn_fused, dim3(BLOCKS), dim3(THREADS),
                               args, 0, stream);
}

// Round 6
// 85.439 us; speedup vs baseline: 1.6794x; 1.6139x over previous
//
#include <hip/hip_runtime.h>
#include <math.h>

#define NW 16
#define NEUR 32
#define TTAB 8192            // global F-table nodes over [0,1]
#define WSUB 0.0625f         // 1/16, exact in fp32
#define INV_SIGMA 200.0f     // 1/0.005
#define OMEGA 15.0f
#define WTHRESH 1e-5f
#define EVAL_BLOCKS 512
#define EVAL_THREADS 256

__device__ __forceinline__ float sigmoid_f(float z) {
    return 1.0f / (1.0f + __expf(-z));
}
__device__ __forceinline__ float tanh_fast(float z) {
    // z bounded here; tanh = 1 - 2/(e^{2z}+1)
    const float e = __expf(2.0f * z);
    return 1.0f - 2.0f / (e + 1.0f);
}

// win_c(x) * u_c(x) for window c (full MLP), 0 if masked/out-of-range.
// Register-lean: layer-2 computed 4 outputs at a time and consumed
// immediately into the W3 dot product -> ~45 live floats, no spill.
__device__ __forceinline__ float window_term(
    float x, int c,
    const float* __restrict__ W1, const float* __restrict__ b1,
    const float* __restrict__ W2, const float* __restrict__ b2,
    const float* __restrict__ W3, const float* __restrict__ b3) {
    if (c < 0 || c >= NW) return 0.0f;
    const float s1 = sigmoid_f((x - (float)c * WSUB) * INV_SIGMA);
    const float s2 = sigmoid_f(-(x - (float)(c + 1) * WSUB) * INV_SIGMA);
    const float win = s1 * s2;
    if (win <= WTHRESH) return 0.0f;

    // subdomain normalization constants (exact dyadic, match reference fp64->fp32)
    float mean, sd;
    if (c == 0)            { mean = 0.03515625f; sd = 0.03515625f; }
    else if (c == NW - 1)  { mean = 0.96484375f; sd = 0.03515625f; }
    else                   { mean = ((float)c + 0.5f) * 0.0625f; sd = 0.0390625f; }
    const float xn = (x - mean) / sd;

    const float* __restrict__ W1c = W1 + c * NEUR;
    const float* __restrict__ b1c = b1 + c * NEUR;
    float h1[NEUR];
#pragma unroll
    for (int j = 0; j < NEUR; ++j)
        h1[j] = tanh_fast(fmaf(xn, W1c[j], b1c[j]));

    const float* __restrict__ W2c = W2 + c * NEUR * NEUR;  // [k][j]
    const float* __restrict__ b2c = b2 + c * NEUR;
    const float* __restrict__ W3c = W3 + c * NEUR;
    float acc = b3[c];
#pragma unroll
    for (int j = 0; j < NEUR; j += 4) {
        float a0 = b2c[j], a1 = b2c[j + 1], a2 = b2c[j + 2], a3 = b2c[j + 3];
#pragma unroll
        for (int k = 0; k < NEUR; ++k) {
            const float hk = h1[k];
            const float4 wv = *(const float4*)(W2c + k * NEUR + j);
            a0 = fmaf(hk, wv.x, a0);
            a1 = fmaf(hk, wv.y, a1);
            a2 = fmaf(hk, wv.z, a2);
            a3 = fmaf(hk, wv.w, a3);
        }
        acc = fmaf(tanh_fast(a0), W3c[j],     acc);
        acc = fmaf(tanh_fast(a1), W3c[j + 1], acc);
        acc = fmaf(tanh_fast(a2), W3c[j + 2], acc);
        acc = fmaf(tanh_fast(a3), W3c[j + 3], acc);
    }

    return win * acc;   // U_SD=1, U_MEAN=0
}

// ---------- K1: build pre-summed F table. 128 blocks x 192 threads ----------
// wave w = d (window offset), lane l = node within block's 64-node span.
__global__ __launch_bounds__(192) void build_F(
    const float* __restrict__ W1, const float* __restrict__ b1,
    const float* __restrict__ W2, const float* __restrict__ b2,
    const float* __restrict__ W3, const float* __restrict__ b3,
    float* __restrict__ F_ws) {
    __shared__ float partial[3][64];
    const int t = threadIdx.x;
    const int d = t >> 6;          // 0,1,2 (wave-uniform)
    const int l = t & 63;
    const int g = blockIdx.x * 64 + l;

    const float xg = (float)g * (1.0f / (float)(TTAB - 1));
    int i0 = (int)(xg * 16.0f);
    if (i0 > NW - 1) i0 = NW - 1;
    partial[d][l] = window_term(xg, i0 - 1 + d, W1, b1, W2, b2, W3, b3);
    __syncthreads();
    if (t < 64)
        F_ws[g] = partial[0][l] + partial[1][l] + partial[2][l];
}

// ---------- K2: stage F into LDS; per point one lerp + tanh(15x) ----------
__global__ __launch_bounds__(EVAL_THREADS) void eval_F(
    const float* __restrict__ x, const float* __restrict__ F_ws,
    float* __restrict__ out, int n) {
    __shared__ float F[TTAB];   // 32 KB

    {
        const float4* __restrict__ src = (const float4*)F_ws;
        float4* dst = (float4*)F;
#pragma unroll
        for (int i = threadIdx.x; i < TTAB / 4; i += EVAL_THREADS)
            dst[i] = src[i];
    }
    __syncthreads();

    const int n4 = n >> 2;
    const int stride = gridDim.x * blockDim.x;
    for (int idx = blockIdx.x * blockDim.x + threadIdx.x; idx < n4; idx += stride) {
        const float4 xv = *(const float4*)(x + idx * 4);
        float4 r;
#pragma unroll
        for (int e = 0; e < 4; ++e) {
            const float xe = (&xv.x)[e];
            float tt = xe * (float)(TTAB - 1);
            tt = fminf(fmaxf(tt, 0.0f), (float)(TTAB - 1) - 0.5f);
            const int it = (int)tt;
            const float f = tt - (float)it;
            const float u0 = F[it];
            const float u1 = F[it + 1];
            const float u = fmaf(f, u1 - u0, u0);
            (&r.x)[e] = tanh_fast(OMEGA * xe) * u;
        }
        *(float4*)(out + idx * 4) = r;
    }
    if (blockIdx.x == 0) {
        const int tail = n & 3;
        if ((int)threadIdx.x < tail) {
            const float xe = x[n4 * 4 + threadIdx.x];
            float tt = xe * (float)(TTAB - 1);
            tt = fminf(fmaxf(tt, 0.0f), (float)(TTAB - 1) - 0.5f);
            const int it = (int)tt;
            const float f = tt - (float)it;
            const float u = fmaf(f, F[it + 1] - F[it], F[it]);
            out[n4 * 4 + threadIdx.x] = tanh_fast(OMEGA * xe) * u;
        }
    }
}

extern "C" void kernel_launch(void* const* d_in, const int* in_sizes, int n_in,
                              void* d_out, int out_size, void* d_ws, size_t ws_size,
                              hipStream_t stream) {
    const float* x  = (const float*)d_in[0];
    const float* W1 = (const float*)d_in[1];
    const float* b1 = (const float*)d_in[2];
    const float* W2 = (const float*)d_in[3];
    const float* b2 = (const float*)d_in[4];
    const float* W3 = (const float*)d_in[5];
    const float* b3 = (const float*)d_in[6];
    float* out = (float*)d_out;
    float* F_ws = (float*)d_ws;   // TTAB floats = 32 KB
    const int n = in_sizes[0];

    build_F<<<TTAB / 64, 192, 0, stream>>>(W1, b1, W2, b2, W3, b3, F_ws);
    eval_F<<<EVAL_BLOCKS, EVAL_THREADS, 0, stream>>>(x, F_ws, out, n);
}